// Round 20
// baseline (301.927 us; speedup 1.0000x reference)
//
#include <hip/hip_runtime.h>
#include <hip/hip_bf16.h>
#include <stdint.h>

typedef __attribute__((ext_vector_type(8))) __bf16 bf16x8;
typedef __attribute__((ext_vector_type(4))) float f32x4;
typedef __attribute__((ext_vector_type(16))) float f32x16;
typedef __attribute__((ext_vector_type(4))) unsigned int u32x4;

#define HIDDEN 1024
#define HEADS 16
#define HD 64
#define NB 4
#define T_ 2048
#define M_ROWS (NB * T_)  // 8192
#define SCL2 0.18033688f  // log2(e)/sqrt(64)
#define FIXM 32.0f        // fixed softmax shift (exact-cancel in normalize)

__device__ __forceinline__ unsigned short f2bf(float x) {
  unsigned u = __builtin_bit_cast(unsigned, x);
  u += 0x7fff + ((u >> 16) & 1);
  return (unsigned short)(u >> 16);
}

__device__ __forceinline__ unsigned pk2(float a, float b) {
  unsigned ua = __builtin_bit_cast(unsigned, a) + 0x8000u;
  unsigned ub = __builtin_bit_cast(unsigned, b) + 0x8000u;
  return __builtin_amdgcn_perm(ub, ua, 0x07060302);
}

__device__ __forceinline__ f32x4 mfma16(bf16x8 a, bf16x8 b, f32x4 c) {
  return __builtin_amdgcn_mfma_f32_16x16x32_bf16(a, b, c, 0, 0, 0);
}
__device__ __forceinline__ f32x16 mfma32(bf16x8 a, bf16x8 b, f32x16 c) {
  return __builtin_amdgcn_mfma_f32_32x32x16_bf16(a, b, c, 0, 0, 0);
}

__device__ __forceinline__ void lds16(const void* g, void* l) {
  __builtin_amdgcn_global_load_lds(
      (const __attribute__((address_space(1))) unsigned int*)g,
      (__attribute__((address_space(3))) unsigned int*)l, 16, 0, 0);
}

__device__ __forceinline__ bf16x8 ldg8(const unsigned short* p) {
  return __builtin_bit_cast(bf16x8, *(const u32x4*)p);
}

// ---------------- fused f32 -> bf16 convert (3 tensors, 1 launch) --------
__global__ void cvt3(const float* __restrict__ i0, unsigned short* __restrict__ o0,
                     int n0, const float* __restrict__ i1,
                     unsigned short* __restrict__ o1, int n1,
                     const float* __restrict__ i2,
                     unsigned short* __restrict__ o2, int n2) {
  int i = blockIdx.x * blockDim.x + threadIdx.x;
  int stride = gridDim.x * blockDim.x;
  int tot = n0 + n1 + n2;
  for (; i < tot; i += stride) {
    const float* src;
    unsigned short* dst;
    int j = i;
    if (j < n0) {
      src = i0; dst = o0;
    } else if ((j -= n0) < n1) {
      src = i1; dst = o1;
    } else {
      j -= n1; src = i2; dst = o2;
    }
    float4 v = ((const float4*)src)[j];
    ushort4 o;
    o.x = f2bf(v.x); o.y = f2bf(v.y); o.z = f2bf(v.z); o.w = f2bf(v.w);
    ((ushort4*)dst)[j] = o;
  }
}

// ====== wide-reuse GEMM, DOUBLE-buffered, 3 blocks/CU ======
// BM=128 BN=256 BK=32, 256 thr = 4 waves (2M x 2N), wave 64x128, acc 4x8.
// r19 falsified LDS-port theory (reuse -25%, time flat); per-tile audit
// shows phase SERIALIZATION (2050 cyc measured vs 622 MFMA-max) + QKV tail
// waste (768 blocks @ 2/CU = 1.5 gens). Fix: 48KB double-buffer -> 3
// blocks/CU: 768 blocks = ONE generation, and 3 anti-phase blocks overlap
// each other's stage/read/MFMA phases. launch_bounds(256,3); natural VGPR
// 96 (r19-measured) fits all cap interpretations (session law r7/r17).
// Layout/swizzle/epilogue byte-identical to r19 (passed, absmax 0.0078).

#define RD(BUF, OFF) \
  __builtin_bit_cast(bf16x8, *(const u32x4*)((BUF) + (OFF)))

template <int EPI, int NTC>
__global__ __launch_bounds__(256, 3) void gemmW(
    const unsigned short* __restrict__ A, const unsigned short* __restrict__ Bm,
    const float* __restrict__ bias, unsigned short* __restrict__ Qb,
    unsigned short* __restrict__ Kb, unsigned short* __restrict__ Vtb,
    float* __restrict__ Cf) {
  constexpr int K = 1024;
  constexpr int N = NTC * 256;
  __shared__ __align__(16) char LB[2][24576];  // per buf: A 8KB @0, B 16KB @8192
  const int tid = threadIdx.x;
  const int wv = tid >> 6, lane = tid & 63;
  const int l16 = lane & 15, grp = lane >> 4;
  const int wm = wv >> 1, wn = wv & 1;
  const int bid = blockIdx.x;
  const int xcd = bid & 7, il = bid >> 3;
  const int bx = il >> 3, by = xcd * 8 + (il & 7);  // bijective
  const int brow0 = by * 128, bcol0 = bx * 256;

  // staging source (pre-swizzled; LDS dest linear per-wave base + lane*16)
  const int ua = (tid & 7) ^ ((tid >> 3) & 7);
  const unsigned short* aptr =
      A + (size_t)(brow0 + (tid >> 3) * 2 + (ua >> 2)) * K + (ua & 3) * 8;
  const unsigned short* bptr =
      Bm + (size_t)(bcol0 + (tid >> 3) * 2 + (ua >> 2)) * K + (ua & 3) * 8;

  // ds_read: logical row R -> phys (R>>1)*128 + (((R&1)*4+grp)^((R>>1)&7))*16
  const int swu = ((((l16 & 1) * 4) + grp) ^ ((l16 >> 1) & 7)) * 16;
  const int aoff = (wm * 32 + (l16 >> 1)) * 128 + swu;          // + m*1024
  const int boff = 8192 + (wn * 64 + (l16 >> 1)) * 128 + swu;   // + n*1024

#define STAGE(c, t)                                                        \
  do {                                                                     \
    lds16(aptr + (size_t)(t) * 32, (char*)LB[c] + wv * 1024);              \
    lds16(aptr + (size_t)64 * K + (size_t)(t) * 32,                        \
          (char*)LB[c] + 4096 + wv * 1024);                                \
    lds16(bptr + (size_t)(t) * 32, (char*)LB[c] + 8192 + wv * 1024);       \
    lds16(bptr + (size_t)64 * K + (size_t)(t) * 32,                        \
          (char*)LB[c] + 12288 + wv * 1024);                               \
    lds16(bptr + (size_t)128 * K + (size_t)(t) * 32,                       \
          (char*)LB[c] + 16384 + wv * 1024);                               \
    lds16(bptr + (size_t)192 * K + (size_t)(t) * 32,                       \
          (char*)LB[c] + 20480 + wv * 1024);                               \
  } while (0)

  f32x4 acc[4][8];
#pragma unroll
  for (int m = 0; m < 4; m++)
#pragma unroll
    for (int n = 0; n < 8; n++) acc[m][n] = (f32x4){0.f, 0.f, 0.f, 0.f};

  STAGE(0, 0);
  asm volatile("s_waitcnt vmcnt(0)" ::: "memory");
  __builtin_amdgcn_sched_barrier(0);
  __builtin_amdgcn_s_barrier();

#pragma unroll 1
  for (int t = 0; t < 32; ++t) {
    const int cb = t & 1;
    if (t < 31) STAGE(cb ^ 1, t + 1);  // async prefetch into other buffer
    const char* buf = (const char*)LB[cb];
    bf16x8 af[4], bfr[8];
#pragma unroll
    for (int m = 0; m < 4; m++) af[m] = RD(buf, aoff + m * 1024);
#pragma unroll
    for (int n = 0; n < 8; n++) bfr[n] = RD(buf, boff + n * 1024);
    __builtin_amdgcn_s_setprio(1);
#pragma unroll
    for (int m = 0; m < 4; m++)
#pragma unroll
      for (int n = 0; n < 8; n++) acc[m][n] = mfma16(af[m], bfr[n], acc[m][n]);
    __builtin_amdgcn_s_setprio(0);
    if (t < 31) {
      asm volatile("s_waitcnt vmcnt(0)" ::: "memory");  // next tile staged
      __builtin_amdgcn_sched_barrier(0);
      __builtin_amdgcn_s_barrier();
    }
  }

  // epilogue (proven scatter; wave geometry 2M x 2N, 64x128 tile)
#pragma unroll
  for (int m = 0; m < 4; m++) {
#pragma unroll
    for (int n = 0; n < 8; n++) {
      int col = bcol0 + wn * 128 + n * 16 + l16;
      int row0 = brow0 + wm * 64 + m * 16 + grp * 4;
      float bs = bias[col];
      if (EPI == 0) {
        int part = col >> 10, rem = col & 1023;
        int h = rem >> 6, d = rem & 63;
#pragma unroll
        for (int r = 0; r < 4; r++) {
          int rw = row0 + r;
          int b = rw >> 11, t = rw & 2047;
          unsigned short val = f2bf(acc[m][n][r] + bs);
          size_t bh = (size_t)(b * 16 + h);
          if (part == 0)
            Qb[(bh * T_ + t) * HD + d] = val;
          else if (part == 1)
            Kb[(bh * T_ + t) * HD + d] = val;
          else {
            int k = t & 31;
            int rr = (k & 3) + 4 * (k >> 3);
            int s = (rr & 7) + 8 * ((k >> 2) & 1) + 16 * (rr >> 3);
            Vtb[(bh * HD + d) * T_ + (t & ~31) + s] = val;
          }
        }
      } else {
#pragma unroll
        for (int r = 0; r < 4; r++)
          Cf[(size_t)(row0 + r) * N + col] = acc[m][n][r] + bs;
      }
    }
  }
#undef STAGE
}

// ---------------- causal flash attention, LDS-shared K/V, KVBLK=64 -------
__global__ __launch_bounds__(256, 3) void attn32(
    const unsigned short* __restrict__ Q, const unsigned short* __restrict__ K,
    const unsigned short* __restrict__ Vt, unsigned short* __restrict__ Ao) {
  __shared__ __align__(16) unsigned short Kl[2][64 * 64];
  __shared__ __align__(16) unsigned short Vl[2][64 * 64];
  const int i = blockIdx.x;
  const int bh = i & 63;
  const int g = (i < 512) ? (15 - (i >> 6)) : ((i - 512) >> 6);
  const int wv = threadIdx.x >> 6, lane = threadIdx.x & 63;
  const int l31 = lane & 31, hi = lane >> 5;
  const int qt = g * 4 + wv;
  const int kmax = g * 2 + 1;
  const unsigned short* Qh = Q + (size_t)bh * T_ * HD;
  const unsigned short* Kh = K + (size_t)bh * T_ * HD;
  const unsigned short* Vh = Vt + (size_t)bh * HD * T_;
  const int b_ = bh >> 4, h_ = bh & 15;

  const int sj = threadIdx.x >> 3, su = threadIdx.x & 7;
  const int sup = su ^ (sj & 7);
  const unsigned short* ksrc = Kh + sj * HD + sup * 8;
  const unsigned short* vsrc =
      Vh + (size_t)(sj + 32 * (sup >> 2)) * T_ + (sup & 3) * 8;

#define STAGE(B, C2)                                                      \
  do {                                                                    \
    int kt_ = (C2) * 64;                                                  \
    char* kd = (char*)&Kl[(B)][0] + wv * 1024;                            \
    char* vd = (char*)&Vl[(B)][0] + wv * 1024;                            \
    lds16(ksrc + (size_t)kt_ * HD, kd);                                   \
    lds16(ksrc + (size_t)(kt_ + 32) * HD, kd + 4096);                     \
    lds16(vsrc + kt_, vd);                                                \
    lds16(vsrc + kt_ + 32, vd + 4096);                                    \
  } while (0)

  int rdoff[4];
#pragma unroll
  for (int ks = 0; ks < 4; ks++)
    rdoff[ks] = l31 * 128 + (((2 * ks + hi) ^ (l31 & 7)) << 4);

  bf16x8 qf[4];
  const int qbase = qt * 32;
#pragma unroll
  for (int st = 0; st < 4; st++)
    qf[st] = ldg8(&Qh[(size_t)(qbase + l31) * HD + st * 16 + hi * 8]);

  f32x16 o0, o1;
#pragma unroll
  for (int r = 0; r < 16; r++) { o0[r] = 0.f; o1[r] = 0.f; }
  float rl = 0.f;

#define CHUNKH(B, H, MASKED)                                                 \
  do {                                                                       \
    const char* kb = (const char*)&Kl[(B)][0] + (H) * 4096;                  \
    const char* vb = (const char*)&Vl[(B)][0] + (H) * 4096;                  \
    bf16x8 KF[4], VF[4];                                                     \
    _Pragma("unroll") for (int ks = 0; ks < 4; ks++) {                       \
      KF[ks] = __builtin_bit_cast(bf16x8, *(const u32x4*)(kb + rdoff[ks]));  \
      VF[ks] = __builtin_bit_cast(bf16x8, *(const u32x4*)(vb + rdoff[ks]));  \
    }                                                                        \
    f32x16 sa;                                                               \
    _Pragma("unroll") for (int r = 0; r < 16; r++) sa[r] = 0.f;              \
    sa = mfma32(KF[0], qf[0], sa);                                           \
    sa = mfma32(KF[1], qf[1], sa);                                           \
    sa = mfma32(KF[2], qf[2], sa);                                           \
    sa = mfma32(KF[3], qf[3], sa);                                           \
    float pv[16];                                                            \
    _Pragma("unroll") for (int r = 0; r < 16; r++) {                         \
      float arg = __builtin_fmaf(sa[r], SCL2, -FIXM);                        \
      if (MASKED) {                                                          \
        int key = (r & 3) + 8 * (r >> 2) + 4 * hi;                           \
        if (key > l31) arg = -1e30f;                                         \
      }                                                                      \
      pv[r] = exp2f(arg);                                                    \
      rl += pv[r];                                                           \
    }                                                                        \
    u32x4 pa0u, pa1u;                                                        \
    pa0u.x = pk2(pv[0], pv[1]);                                              \
    pa0u.y = pk2(pv[2], pv[3]);                                              \
    pa0u.z = pk2(pv[4], pv[5]);                                              \
    pa0u.w = pk2(pv[6], pv[7]);                                              \
    pa1u.x = pk2(pv[8], pv[9]);                                              \
    pa1u.y = pk2(pv[10], pv[11]);                                            \
    pa1u.z = pk2(pv[12], pv[13]);                                            \
    pa1u.w = pk2(pv[14], pv[15]);                                            \
    bf16x8 pa0 = __builtin_bit_cast(bf16x8, pa0u);                           \
    bf16x8 pa1 = __builtin_bit_cast(bf16x8, pa1u);                           \
    o0 = mfma32(VF[0], pa0, o0);                                             \
    o0 = mfma32(VF[1], pa1, o0);                                             \
    o1 = mfma32(VF[2], pa0, o1);                                             \
    o1 = mfma32(VF[3], pa1, o1);                                             \
  } while (0)

  STAGE(0, 0);
  __syncthreads();
  int cur = 0;
  const int halfq = qt >> 1, oddq = qt & 1;
  for (int kc2 = 0; kc2 <= kmax; kc2++) {
    if (kc2 < kmax) STAGE(cur ^ 1, kc2 + 1);
    if (kc2 < halfq) {
      CHUNKH(cur, 0, 0);
      CHUNKH(cur, 1, 0);
    } else if (kc2 == halfq) {
      if (oddq) {
        CHUNKH(cur, 0, 0);
        CHUNKH(cur, 1, 1);
      } else {
        CHUNKH(cur, 0, 1);
      }
    }
    __syncthreads();
    cur ^= 1;
  }

  float rlt = rl + __shfl_xor(rl, 32);
  float inv = 1.f / rlt;
  const size_t base =
      ((size_t)b_ * T_ + qbase + l31) * HIDDEN + h_ * HD + hi * 4;
#pragma unroll
  for (int gg = 0; gg < 4; gg++) {
    uint2 u;
    u.x = pk2(o0[4 * gg] * inv, o0[4 * gg + 1] * inv);
    u.y = pk2(o0[4 * gg + 2] * inv, o0[4 * gg + 3] * inv);
    *(uint2*)&Ao[base + gg * 8] = u;
  }
#pragma unroll
  for (int gg = 0; gg < 4; gg++) {
    uint2 u;
    u.x = pk2(o1[4 * gg] * inv, o1[4 * gg + 1] * inv);
    u.y = pk2(o1[4 * gg + 2] * inv, o1[4 * gg + 3] * inv);
    *(uint2*)&Ao[base + 32 + gg * 8] = u;
  }
#undef STAGE
#undef CHUNKH
}

extern "C" void kernel_launch(void* const* d_in, const int* in_sizes, int n_in,
                              void* d_out, int out_size, void* d_ws,
                              size_t ws_size, hipStream_t stream) {
  const float* data = (const float*)d_in[0];
  const float* qkvw = (const float*)d_in[1];
  const float* qkvb = (const float*)d_in[2];
  const float* outw = (const float*)d_in[3];
  const float* outb = (const float*)d_in[4];
  float* out = (float*)d_out;
  char* ws = (char*)d_ws;

  unsigned short* dataBf = (unsigned short*)(ws);             // 16 MiB, reused as attnO
  unsigned short* qkvwBf = (unsigned short*)(ws + 16777216);  // 6 MiB
  unsigned short* outwBf = (unsigned short*)(ws + 23068672);  // 2 MiB
  unsigned short* Qb = (unsigned short*)(ws + 25165824);      // 16 MiB
  unsigned short* Kb = (unsigned short*)(ws + 41943040);      // 16 MiB
  unsigned short* Vtb = (unsigned short*)(ws + 58720256);     // 16 MiB
  unsigned short* attnO = dataBf;  // safe: dataBf dead after QKV GEMM

  cvt3<<<2048, 256, 0, stream>>>(data, dataBf, (M_ROWS * HIDDEN) / 4, qkvw,
                                 qkvwBf, (3 * HIDDEN * HIDDEN) / 4, outw,
                                 outwBf, (HIDDEN * HIDDEN) / 4);

  gemmW<0, 12><<<768, 256, 0, stream>>>(dataBf, qkvwBf, qkvb, Qb, Kb, Vtb,
                                        nullptr);
  attn32<<<1024, 256, 0, stream>>>(Qb, Kb, Vtb, attnO);
  gemmW<1, 4><<<256, 256, 0, stream>>>(attnO, outwBf, outb, nullptr, nullptr,
                                       nullptr, out);
}

// Round 21
// 185.363 us; speedup vs baseline: 1.6288x; 1.6288x over previous
//
#include <hip/hip_runtime.h>
#include <hip/hip_bf16.h>
#include <stdint.h>

typedef __attribute__((ext_vector_type(8))) __bf16 bf16x8;
typedef __attribute__((ext_vector_type(4))) float f32x4;
typedef __attribute__((ext_vector_type(16))) float f32x16;
typedef __attribute__((ext_vector_type(4))) unsigned int u32x4;

#define HIDDEN 1024
#define HEADS 16
#define HD 64
#define NB 4
#define T_ 2048
#define M_ROWS (NB * T_)  // 8192
#define SCL2 0.18033688f  // log2(e)/sqrt(64)
#define FIXM 32.0f        // fixed softmax shift (exact-cancel in normalize)

__device__ __forceinline__ unsigned short f2bf(float x) {
  unsigned u = __builtin_bit_cast(unsigned, x);
  u += 0x7fff + ((u >> 16) & 1);
  return (unsigned short)(u >> 16);
}

__device__ __forceinline__ unsigned pk2(float a, float b) {
  unsigned ua = __builtin_bit_cast(unsigned, a) + 0x8000u;
  unsigned ub = __builtin_bit_cast(unsigned, b) + 0x8000u;
  return __builtin_amdgcn_perm(ub, ua, 0x07060302);
}

__device__ __forceinline__ f32x4 mfma16(bf16x8 a, bf16x8 b, f32x4 c) {
  return __builtin_amdgcn_mfma_f32_16x16x32_bf16(a, b, c, 0, 0, 0);
}
__device__ __forceinline__ f32x16 mfma32(bf16x8 a, bf16x8 b, f32x16 c) {
  return __builtin_amdgcn_mfma_f32_32x32x16_bf16(a, b, c, 0, 0, 0);
}

__device__ __forceinline__ void lds16(const void* g, void* l) {
  __builtin_amdgcn_global_load_lds(
      (const __attribute__((address_space(1))) unsigned int*)g,
      (__attribute__((address_space(3))) unsigned int*)l, 16, 0, 0);
}

__device__ __forceinline__ bf16x8 ldg8(const unsigned short* p) {
  return __builtin_bit_cast(bf16x8, *(const u32x4*)p);
}

// ---------------- fused f32 -> bf16 convert (3 tensors, 1 launch) --------
__global__ void cvt3(const float* __restrict__ i0, unsigned short* __restrict__ o0,
                     int n0, const float* __restrict__ i1,
                     unsigned short* __restrict__ o1, int n1,
                     const float* __restrict__ i2,
                     unsigned short* __restrict__ o2, int n2) {
  int i = blockIdx.x * blockDim.x + threadIdx.x;
  int stride = gridDim.x * blockDim.x;
  int tot = n0 + n1 + n2;
  for (; i < tot; i += stride) {
    const float* src;
    unsigned short* dst;
    int j = i;
    if (j < n0) {
      src = i0; dst = o0;
    } else if ((j -= n0) < n1) {
      src = i1; dst = o1;
    } else {
      j -= n1; src = i2; dst = o2;
    }
    float4 v = ((const float4*)src)[j];
    ushort4 o;
    o.x = f2bf(v.x); o.y = f2bf(v.y); o.z = f2bf(v.z); o.w = f2bf(v.w);
    ((ushort4*)dst)[j] = o;
  }
}

// ====== wide-reuse GEMM: BM=128 BN=256 BK=32, wave tile 64x128 ======
// FINAL (r19 config, session best 185.2us). 256 thr = 4 waves (2M x 2N),
// acc 4x8. Triple-buffered 72KB, counted distance-2 vmcnt(6), 1 barrier
// per tile, 32 MFMA/barrier. r13-verified packed-row conflict-free layout
// + both-sides XOR swizzle. XCD-panel L2 mapping (r16: FETCH 103->41MB).
// SESSION LAWS: (1) r7/r17/r20 - never tighten launch_bounds below the
// compiler's natural VGPR choice (here 96 @ (256,2)); every violation
// spilled (483MB scratch writes in r20). (2) permlane self-swap
// miscompiles (r2-r5). (3) L2-thrash was the one real GEMM lever (+10%);
// schedule micro-variants (r13/r14/r17/r20) all regressed or were flat.

#define RD(BUF, OFF) \
  __builtin_bit_cast(bf16x8, *(const u32x4*)((BUF) + (OFF)))

template <int EPI, int NTC>
__global__ __launch_bounds__(256, 2) void gemmW(
    const unsigned short* __restrict__ A, const unsigned short* __restrict__ Bm,
    const float* __restrict__ bias, unsigned short* __restrict__ Qb,
    unsigned short* __restrict__ Kb, unsigned short* __restrict__ Vtb,
    float* __restrict__ Cf) {
  constexpr int K = 1024;
  constexpr int N = NTC * 256;
  __shared__ __align__(16) char LB[3][24576];  // per buf: A 8KB @0, B 16KB @8192
  const int tid = threadIdx.x;
  const int wv = tid >> 6, lane = tid & 63;
  const int l16 = lane & 15, grp = lane >> 4;
  const int wm = wv >> 1, wn = wv & 1;
  const int bid = blockIdx.x;
  const int xcd = bid & 7, il = bid >> 3;
  const int bx = il >> 3, by = xcd * 8 + (il & 7);  // bijective
  const int brow0 = by * 128, bcol0 = bx * 256;

  // staging source (pre-swizzled; LDS dest linear per-wave base + lane*16)
  const int ua = (tid & 7) ^ ((tid >> 3) & 7);
  const unsigned short* aptr =
      A + (size_t)(brow0 + (tid >> 3) * 2 + (ua >> 2)) * K + (ua & 3) * 8;
  const unsigned short* bptr =
      Bm + (size_t)(bcol0 + (tid >> 3) * 2 + (ua >> 2)) * K + (ua & 3) * 8;

  // ds_read: logical row R -> phys (R>>1)*128 + (((R&1)*4+grp)^((R>>1)&7))*16
  const int swu = ((((l16 & 1) * 4) + grp) ^ ((l16 >> 1) & 7)) * 16;
  const int aoff = (wm * 32 + (l16 >> 1)) * 128 + swu;          // + m*1024
  const int boff = 8192 + (wn * 64 + (l16 >> 1)) * 128 + swu;   // + n*1024

#define STAGE(c, t)                                                        \
  do {                                                                     \
    lds16(aptr + (size_t)(t) * 32, (char*)LB[c] + wv * 1024);              \
    lds16(aptr + (size_t)64 * K + (size_t)(t) * 32,                        \
          (char*)LB[c] + 4096 + wv * 1024);                                \
    lds16(bptr + (size_t)(t) * 32, (char*)LB[c] + 8192 + wv * 1024);       \
    lds16(bptr + (size_t)64 * K + (size_t)(t) * 32,                        \
          (char*)LB[c] + 12288 + wv * 1024);                               \
    lds16(bptr + (size_t)128 * K + (size_t)(t) * 32,                       \
          (char*)LB[c] + 16384 + wv * 1024);                               \
    lds16(bptr + (size_t)192 * K + (size_t)(t) * 32,                       \
          (char*)LB[c] + 20480 + wv * 1024);                               \
  } while (0)

  f32x4 acc[4][8];
#pragma unroll
  for (int m = 0; m < 4; m++)
#pragma unroll
    for (int n = 0; n < 8; n++) acc[m][n] = (f32x4){0.f, 0.f, 0.f, 0.f};

  STAGE(0, 0);
  STAGE(1, 1);
  asm volatile("s_waitcnt vmcnt(6)" ::: "memory");  // tile0 landed, t1 flying
  __builtin_amdgcn_sched_barrier(0);
  __builtin_amdgcn_s_barrier();

  int c = 0, c2 = 2;
#pragma unroll 1
  for (int t = 0; t < 32; ++t) {
    if (t < 30) STAGE(c2, t + 2);
    const char* buf = (const char*)LB[c];
    bf16x8 af[4], bfr[8];
#pragma unroll
    for (int m = 0; m < 4; m++) af[m] = RD(buf, aoff + m * 1024);
#pragma unroll
    for (int n = 0; n < 8; n++) bfr[n] = RD(buf, boff + n * 1024);
    __builtin_amdgcn_s_setprio(1);
#pragma unroll
    for (int m = 0; m < 4; m++)
#pragma unroll
      for (int n = 0; n < 8; n++) acc[m][n] = mfma16(af[m], bfr[n], acc[m][n]);
    __builtin_amdgcn_s_setprio(0);
    if (t < 30) {
      asm volatile("s_waitcnt vmcnt(6)" ::: "memory");
      __builtin_amdgcn_sched_barrier(0);
      __builtin_amdgcn_s_barrier();
    } else if (t == 30) {
      asm volatile("s_waitcnt vmcnt(0)" ::: "memory");
      __builtin_amdgcn_sched_barrier(0);
      __builtin_amdgcn_s_barrier();
    }
    c = (c == 2) ? 0 : c + 1;
    c2 = (c2 == 2) ? 0 : c2 + 1;
  }

  // epilogue (proven scatter; wave geometry 2M x 2N, 64x128 tile)
#pragma unroll
  for (int m = 0; m < 4; m++) {
#pragma unroll
    for (int n = 0; n < 8; n++) {
      int col = bcol0 + wn * 128 + n * 16 + l16;
      int row0 = brow0 + wm * 64 + m * 16 + grp * 4;
      float bs = bias[col];
      if (EPI == 0) {
        int part = col >> 10, rem = col & 1023;
        int h = rem >> 6, d = rem & 63;
#pragma unroll
        for (int r = 0; r < 4; r++) {
          int rw = row0 + r;
          int b = rw >> 11, t = rw & 2047;
          unsigned short val = f2bf(acc[m][n][r] + bs);
          size_t bh = (size_t)(b * 16 + h);
          if (part == 0)
            Qb[(bh * T_ + t) * HD + d] = val;
          else if (part == 1)
            Kb[(bh * T_ + t) * HD + d] = val;
          else {
            int k = t & 31;
            int rr = (k & 3) + 4 * (k >> 3);
            int s = (rr & 7) + 8 * ((k >> 2) & 1) + 16 * (rr >> 3);
            Vtb[(bh * HD + d) * T_ + (t & ~31) + s] = val;
          }
        }
      } else {
#pragma unroll
        for (int r = 0; r < 4; r++)
          Cf[(size_t)(row0 + r) * N + col] = acc[m][n][r] + bs;
      }
    }
  }
#undef STAGE
}

// ---------------- causal flash attention, LDS-shared K/V, KVBLK=64 -------
__global__ __launch_bounds__(256, 3) void attn32(
    const unsigned short* __restrict__ Q, const unsigned short* __restrict__ K,
    const unsigned short* __restrict__ Vt, unsigned short* __restrict__ Ao) {
  __shared__ __align__(16) unsigned short Kl[2][64 * 64];
  __shared__ __align__(16) unsigned short Vl[2][64 * 64];
  const int i = blockIdx.x;
  const int bh = i & 63;
  const int g = (i < 512) ? (15 - (i >> 6)) : ((i - 512) >> 6);
  const int wv = threadIdx.x >> 6, lane = threadIdx.x & 63;
  const int l31 = lane & 31, hi = lane >> 5;
  const int qt = g * 4 + wv;
  const int kmax = g * 2 + 1;
  const unsigned short* Qh = Q + (size_t)bh * T_ * HD;
  const unsigned short* Kh = K + (size_t)bh * T_ * HD;
  const unsigned short* Vh = Vt + (size_t)bh * HD * T_;
  const int b_ = bh >> 4, h_ = bh & 15;

  const int sj = threadIdx.x >> 3, su = threadIdx.x & 7;
  const int sup = su ^ (sj & 7);
  const unsigned short* ksrc = Kh + sj * HD + sup * 8;
  const unsigned short* vsrc =
      Vh + (size_t)(sj + 32 * (sup >> 2)) * T_ + (sup & 3) * 8;

#define STAGE(B, C2)                                                      \
  do {                                                                    \
    int kt_ = (C2) * 64;                                                  \
    char* kd = (char*)&Kl[(B)][0] + wv * 1024;                            \
    char* vd = (char*)&Vl[(B)][0] + wv * 1024;                            \
    lds16(ksrc + (size_t)kt_ * HD, kd);                                   \
    lds16(ksrc + (size_t)(kt_ + 32) * HD, kd + 4096);                     \
    lds16(vsrc + kt_, vd);                                                \
    lds16(vsrc + kt_ + 32, vd + 4096);                                    \
  } while (0)

  int rdoff[4];
#pragma unroll
  for (int ks = 0; ks < 4; ks++)
    rdoff[ks] = l31 * 128 + (((2 * ks + hi) ^ (l31 & 7)) << 4);

  bf16x8 qf[4];
  const int qbase = qt * 32;
#pragma unroll
  for (int st = 0; st < 4; st++)
    qf[st] = ldg8(&Qh[(size_t)(qbase + l31) * HD + st * 16 + hi * 8]);

  f32x16 o0, o1;
#pragma unroll
  for (int r = 0; r < 16; r++) { o0[r] = 0.f; o1[r] = 0.f; }
  float rl = 0.f;

#define CHUNKH(B, H, MASKED)                                                 \
  do {                                                                       \
    const char* kb = (const char*)&Kl[(B)][0] + (H) * 4096;                  \
    const char* vb = (const char*)&Vl[(B)][0] + (H) * 4096;                  \
    bf16x8 KF[4], VF[4];                                                     \
    _Pragma("unroll") for (int ks = 0; ks < 4; ks++) {                       \
      KF[ks] = __builtin_bit_cast(bf16x8, *(const u32x4*)(kb + rdoff[ks]));  \
      VF[ks] = __builtin_bit_cast(bf16x8, *(const u32x4*)(vb + rdoff[ks]));  \
    }                                                                        \
    f32x16 sa;                                                               \
    _Pragma("unroll") for (int r = 0; r < 16; r++) sa[r] = 0.f;              \
    sa = mfma32(KF[0], qf[0], sa);                                           \
    sa = mfma32(KF[1], qf[1], sa);                                           \
    sa = mfma32(KF[2], qf[2], sa);                                           \
    sa = mfma32(KF[3], qf[3], sa);                                           \
    float pv[16];                                                            \
    _Pragma("unroll") for (int r = 0; r < 16; r++) {                         \
      float arg = __builtin_fmaf(sa[r], SCL2, -FIXM);                        \
      if (MASKED) {                                                          \
        int key = (r & 3) + 8 * (r >> 2) + 4 * hi;                           \
        if (key > l31) arg = -1e30f;                                         \
      }                                                                      \
      pv[r] = exp2f(arg);                                                    \
      rl += pv[r];                                                           \
    }                                                                        \
    u32x4 pa0u, pa1u;                                                        \
    pa0u.x = pk2(pv[0], pv[1]);                                              \
    pa0u.y = pk2(pv[2], pv[3]);                                              \
    pa0u.z = pk2(pv[4], pv[5]);                                              \
    pa0u.w = pk2(pv[6], pv[7]);                                              \
    pa1u.x = pk2(pv[8], pv[9]);                                              \
    pa1u.y = pk2(pv[10], pv[11]);                                            \
    pa1u.z = pk2(pv[12], pv[13]);                                            \
    pa1u.w = pk2(pv[14], pv[15]);                                            \
    bf16x8 pa0 = __builtin_bit_cast(bf16x8, pa0u);                           \
    bf16x8 pa1 = __builtin_bit_cast(bf16x8, pa1u);                           \
    o0 = mfma32(VF[0], pa0, o0);                                             \
    o0 = mfma32(VF[1], pa1, o0);                                             \
    o1 = mfma32(VF[2], pa0, o1);                                             \
    o1 = mfma32(VF[3], pa1, o1);                                             \
  } while (0)

  STAGE(0, 0);
  __syncthreads();
  int cur = 0;
  const int halfq = qt >> 1, oddq = qt & 1;
  for (int kc2 = 0; kc2 <= kmax; kc2++) {
    if (kc2 < kmax) STAGE(cur ^ 1, kc2 + 1);
    if (kc2 < halfq) {
      CHUNKH(cur, 0, 0);
      CHUNKH(cur, 1, 0);
    } else if (kc2 == halfq) {
      if (oddq) {
        CHUNKH(cur, 0, 0);
        CHUNKH(cur, 1, 1);
      } else {
        CHUNKH(cur, 0, 1);
      }
    }
    __syncthreads();
    cur ^= 1;
  }

  float rlt = rl + __shfl_xor(rl, 32);
  float inv = 1.f / rlt;
  const size_t base =
      ((size_t)b_ * T_ + qbase + l31) * HIDDEN + h_ * HD + hi * 4;
#pragma unroll
  for (int gg = 0; gg < 4; gg++) {
    uint2 u;
    u.x = pk2(o0[4 * gg] * inv, o0[4 * gg + 1] * inv);
    u.y = pk2(o0[4 * gg + 2] * inv, o0[4 * gg + 3] * inv);
    *(uint2*)&Ao[base + gg * 8] = u;
  }
#pragma unroll
  for (int gg = 0; gg < 4; gg++) {
    uint2 u;
    u.x = pk2(o1[4 * gg] * inv, o1[4 * gg + 1] * inv);
    u.y = pk2(o1[4 * gg + 2] * inv, o1[4 * gg + 3] * inv);
    *(uint2*)&Ao[base + 32 + gg * 8] = u;
  }
#undef STAGE
#undef CHUNKH
}

extern "C" void kernel_launch(void* const* d_in, const int* in_sizes, int n_in,
                              void* d_out, int out_size, void* d_ws,
                              size_t ws_size, hipStream_t stream) {
  const float* data = (const float*)d_in[0];
  const float* qkvw = (const float*)d_in[1];
  const float* qkvb = (const float*)d_in[2];
  const float* outw = (const float*)d_in[3];
  const float* outb = (const float*)d_in[4];
  float* out = (float*)d_out;
  char* ws = (char*)d_ws;

  unsigned short* dataBf = (unsigned short*)(ws);             // 16 MiB, reused as attnO
  unsigned short* qkvwBf = (unsigned short*)(ws + 16777216);  // 6 MiB
  unsigned short* outwBf = (unsigned short*)(ws + 23068672);  // 2 MiB
  unsigned short* Qb = (unsigned short*)(ws + 25165824);      // 16 MiB
  unsigned short* Kb = (unsigned short*)(ws + 41943040);      // 16 MiB
  unsigned short* Vtb = (unsigned short*)(ws + 58720256);     // 16 MiB
  unsigned short* attnO = dataBf;  // safe: dataBf dead after QKV GEMM

  cvt3<<<2048, 256, 0, stream>>>(data, dataBf, (M_ROWS * HIDDEN) / 4, qkvw,
                                 qkvwBf, (3 * HIDDEN * HIDDEN) / 4, outw,
                                 outwBf, (HIDDEN * HIDDEN) / 4);

  gemmW<0, 12><<<768, 256, 0, stream>>>(dataBf, qkvwBf, qkvb, Qb, Kb, Vtb,
                                        nullptr);
  attn32<<<1024, 256, 0, stream>>>(Qb, Kb, Vtb, attnO);
  gemmW<1, 4><<<256, 256, 0, stream>>>(attnO, outwBf, outb, nullptr, nullptr,
                                       nullptr, out);
}

// Round 22
// 181.914 us; speedup vs baseline: 1.6597x; 1.0190x over previous
//
#include <hip/hip_runtime.h>
#include <hip/hip_bf16.h>
#include <stdint.h>

typedef __attribute__((ext_vector_type(8))) __bf16 bf16x8;
typedef __attribute__((ext_vector_type(4))) float f32x4;
typedef __attribute__((ext_vector_type(16))) float f32x16;
typedef __attribute__((ext_vector_type(4))) unsigned int u32x4;

#define HIDDEN 1024
#define HEADS 16
#define HD 64
#define NB 4
#define T_ 2048
#define M_ROWS (NB * T_)  // 8192
#define SCL2 0.18033688f  // log2(e)/sqrt(64)
#define FIXM 32.0f        // fixed softmax shift (exact-cancel in normalize)

__device__ __forceinline__ unsigned short f2bf(float x) {
  unsigned u = __builtin_bit_cast(unsigned, x);
  u += 0x7fff + ((u >> 16) & 1);
  return (unsigned short)(u >> 16);
}

__device__ __forceinline__ unsigned pk2(float a, float b) {
  unsigned ua = __builtin_bit_cast(unsigned, a) + 0x8000u;
  unsigned ub = __builtin_bit_cast(unsigned, b) + 0x8000u;
  return __builtin_amdgcn_perm(ub, ua, 0x07060302);
}

__device__ __forceinline__ f32x4 mfma16(bf16x8 a, bf16x8 b, f32x4 c) {
  return __builtin_amdgcn_mfma_f32_16x16x32_bf16(a, b, c, 0, 0, 0);
}
__device__ __forceinline__ f32x16 mfma32(bf16x8 a, bf16x8 b, f32x16 c) {
  return __builtin_amdgcn_mfma_f32_32x32x16_bf16(a, b, c, 0, 0, 0);
}

__device__ __forceinline__ void lds16(const void* g, void* l) {
  __builtin_amdgcn_global_load_lds(
      (const __attribute__((address_space(1))) unsigned int*)g,
      (__attribute__((address_space(3))) unsigned int*)l, 16, 0, 0);
}

__device__ __forceinline__ bf16x8 ldg8(const unsigned short* p) {
  return __builtin_bit_cast(bf16x8, *(const u32x4*)p);
}

// ---------------- fused f32 -> bf16 convert (3 tensors, 1 launch) --------
__global__ void cvt3(const float* __restrict__ i0, unsigned short* __restrict__ o0,
                     int n0, const float* __restrict__ i1,
                     unsigned short* __restrict__ o1, int n1,
                     const float* __restrict__ i2,
                     unsigned short* __restrict__ o2, int n2) {
  int i = blockIdx.x * blockDim.x + threadIdx.x;
  int stride = gridDim.x * blockDim.x;
  int tot = n0 + n1 + n2;
  for (; i < tot; i += stride) {
    const float* src;
    unsigned short* dst;
    int j = i;
    if (j < n0) {
      src = i0; dst = o0;
    } else if ((j -= n0) < n1) {
      src = i1; dst = o1;
    } else {
      j -= n1; src = i2; dst = o2;
    }
    float4 v = ((const float4*)src)[j];
    ushort4 o;
    o.x = f2bf(v.x); o.y = f2bf(v.y); o.z = f2bf(v.z); o.w = f2bf(v.w);
    ((ushort4*)dst)[j] = o;
  }
}

// ====== wide-reuse GEMM: BM=128 BN=256 BK=32, wave tile 64x128 ======
// r19 config MINUS setprio (r21 hypothesis: setprio(1) around MFMA starves
// the co-resident block's prio-0 waves -> observed zero cross-block overlap
// (QKV 82us = 3 x 27us/block despite 2 blocks/CU). Catalog T5: setprio is
// null-to-NEGATIVE on non-8-phase GEMM (m190), positive on attn (m191) —
// polarity matches. Single-variable test; attn keeps its setprio.
// 256 thr = 4 waves (2M x 2N), acc 4x8. Triple-buffered 72KB, counted
// distance-2 vmcnt(6), 1 barrier/tile, 32 MFMA/barrier. Conflict-free
// packed-row layout + both-sides XOR swizzle. XCD-panel L2 map (r16).
// SESSION LAWS: (1) never tighten launch_bounds below natural VGPR (r7/
// r17/r20 spills); (2) no permlane self-swap (r2-r5 miscompile).

#define RD(BUF, OFF) \
  __builtin_bit_cast(bf16x8, *(const u32x4*)((BUF) + (OFF)))

template <int EPI, int NTC>
__global__ __launch_bounds__(256, 2) void gemmW(
    const unsigned short* __restrict__ A, const unsigned short* __restrict__ Bm,
    const float* __restrict__ bias, unsigned short* __restrict__ Qb,
    unsigned short* __restrict__ Kb, unsigned short* __restrict__ Vtb,
    float* __restrict__ Cf) {
  constexpr int K = 1024;
  constexpr int N = NTC * 256;
  __shared__ __align__(16) char LB[3][24576];  // per buf: A 8KB @0, B 16KB @8192
  const int tid = threadIdx.x;
  const int wv = tid >> 6, lane = tid & 63;
  const int l16 = lane & 15, grp = lane >> 4;
  const int wm = wv >> 1, wn = wv & 1;
  const int bid = blockIdx.x;
  const int xcd = bid & 7, il = bid >> 3;
  const int bx = il >> 3, by = xcd * 8 + (il & 7);  // bijective
  const int brow0 = by * 128, bcol0 = bx * 256;

  // staging source (pre-swizzled; LDS dest linear per-wave base + lane*16)
  const int ua = (tid & 7) ^ ((tid >> 3) & 7);
  const unsigned short* aptr =
      A + (size_t)(brow0 + (tid >> 3) * 2 + (ua >> 2)) * K + (ua & 3) * 8;
  const unsigned short* bptr =
      Bm + (size_t)(bcol0 + (tid >> 3) * 2 + (ua >> 2)) * K + (ua & 3) * 8;

  // ds_read: logical row R -> phys (R>>1)*128 + (((R&1)*4+grp)^((R>>1)&7))*16
  const int swu = ((((l16 & 1) * 4) + grp) ^ ((l16 >> 1) & 7)) * 16;
  const int aoff = (wm * 32 + (l16 >> 1)) * 128 + swu;          // + m*1024
  const int boff = 8192 + (wn * 64 + (l16 >> 1)) * 128 + swu;   // + n*1024

#define STAGE(c, t)                                                        \
  do {                                                                     \
    lds16(aptr + (size_t)(t) * 32, (char*)LB[c] + wv * 1024);              \
    lds16(aptr + (size_t)64 * K + (size_t)(t) * 32,                        \
          (char*)LB[c] + 4096 + wv * 1024);                                \
    lds16(bptr + (size_t)(t) * 32, (char*)LB[c] + 8192 + wv * 1024);       \
    lds16(bptr + (size_t)64 * K + (size_t)(t) * 32,                        \
          (char*)LB[c] + 12288 + wv * 1024);                               \
    lds16(bptr + (size_t)128 * K + (size_t)(t) * 32,                       \
          (char*)LB[c] + 16384 + wv * 1024);                               \
    lds16(bptr + (size_t)192 * K + (size_t)(t) * 32,                       \
          (char*)LB[c] + 20480 + wv * 1024);                               \
  } while (0)

  f32x4 acc[4][8];
#pragma unroll
  for (int m = 0; m < 4; m++)
#pragma unroll
    for (int n = 0; n < 8; n++) acc[m][n] = (f32x4){0.f, 0.f, 0.f, 0.f};

  STAGE(0, 0);
  STAGE(1, 1);
  asm volatile("s_waitcnt vmcnt(6)" ::: "memory");  // tile0 landed, t1 flying
  __builtin_amdgcn_sched_barrier(0);
  __builtin_amdgcn_s_barrier();

  int c = 0, c2 = 2;
#pragma unroll 1
  for (int t = 0; t < 32; ++t) {
    if (t < 30) STAGE(c2, t + 2);
    const char* buf = (const char*)LB[c];
    bf16x8 af[4], bfr[8];
#pragma unroll
    for (int m = 0; m < 4; m++) af[m] = RD(buf, aoff + m * 1024);
#pragma unroll
    for (int n = 0; n < 8; n++) bfr[n] = RD(buf, boff + n * 1024);
#pragma unroll
    for (int m = 0; m < 4; m++)
#pragma unroll
      for (int n = 0; n < 8; n++) acc[m][n] = mfma16(af[m], bfr[n], acc[m][n]);
    if (t < 30) {
      asm volatile("s_waitcnt vmcnt(6)" ::: "memory");
      __builtin_amdgcn_sched_barrier(0);
      __builtin_amdgcn_s_barrier();
    } else if (t == 30) {
      asm volatile("s_waitcnt vmcnt(0)" ::: "memory");
      __builtin_amdgcn_sched_barrier(0);
      __builtin_amdgcn_s_barrier();
    }
    c = (c == 2) ? 0 : c + 1;
    c2 = (c2 == 2) ? 0 : c2 + 1;
  }

  // epilogue (proven scatter; wave geometry 2M x 2N, 64x128 tile)
#pragma unroll
  for (int m = 0; m < 4; m++) {
#pragma unroll
    for (int n = 0; n < 8; n++) {
      int col = bcol0 + wn * 128 + n * 16 + l16;
      int row0 = brow0 + wm * 64 + m * 16 + grp * 4;
      float bs = bias[col];
      if (EPI == 0) {
        int part = col >> 10, rem = col & 1023;
        int h = rem >> 6, d = rem & 63;
#pragma unroll
        for (int r = 0; r < 4; r++) {
          int rw = row0 + r;
          int b = rw >> 11, t = rw & 2047;
          unsigned short val = f2bf(acc[m][n][r] + bs);
          size_t bh = (size_t)(b * 16 + h);
          if (part == 0)
            Qb[(bh * T_ + t) * HD + d] = val;
          else if (part == 1)
            Kb[(bh * T_ + t) * HD + d] = val;
          else {
            int k = t & 31;
            int rr = (k & 3) + 4 * (k >> 3);
            int s = (rr & 7) + 8 * ((k >> 2) & 1) + 16 * (rr >> 3);
            Vtb[(bh * HD + d) * T_ + (t & ~31) + s] = val;
          }
        }
      } else {
#pragma unroll
        for (int r = 0; r < 4; r++)
          Cf[(size_t)(row0 + r) * N + col] = acc[m][n][r] + bs;
      }
    }
  }
#undef STAGE
}

// ---------------- causal flash attention, LDS-shared K/V, KVBLK=64 -------
__global__ __launch_bounds__(256, 3) void attn32(
    const unsigned short* __restrict__ Q, const unsigned short* __restrict__ K,
    const unsigned short* __restrict__ Vt, unsigned short* __restrict__ Ao) {
  __shared__ __align__(16) unsigned short Kl[2][64 * 64];
  __shared__ __align__(16) unsigned short Vl[2][64 * 64];
  const int i = blockIdx.x;
  const int bh = i & 63;
  const int g = (i < 512) ? (15 - (i >> 6)) : ((i - 512) >> 6);
  const int wv = threadIdx.x >> 6, lane = threadIdx.x & 63;
  const int l31 = lane & 31, hi = lane >> 5;
  const int qt = g * 4 + wv;
  const int kmax = g * 2 + 1;
  const unsigned short* Qh = Q + (size_t)bh * T_ * HD;
  const unsigned short* Kh = K + (size_t)bh * T_ * HD;
  const unsigned short* Vh = Vt + (size_t)bh * HD * T_;
  const int b_ = bh >> 4, h_ = bh & 15;

  const int sj = threadIdx.x >> 3, su = threadIdx.x & 7;
  const int sup = su ^ (sj & 7);
  const unsigned short* ksrc = Kh + sj * HD + sup * 8;
  const unsigned short* vsrc =
      Vh + (size_t)(sj + 32 * (sup >> 2)) * T_ + (sup & 3) * 8;

#define STAGE(B, C2)                                                      \
  do {                                                                    \
    int kt_ = (C2) * 64;                                                  \
    char* kd = (char*)&Kl[(B)][0] + wv * 1024;                            \
    char* vd = (char*)&Vl[(B)][0] + wv * 1024;                            \
    lds16(ksrc + (size_t)kt_ * HD, kd);                                   \
    lds16(ksrc + (size_t)(kt_ + 32) * HD, kd + 4096);                     \
    lds16(vsrc + kt_, vd);                                                \
    lds16(vsrc + kt_ + 32, vd + 4096);                                    \
  } while (0)

  int rdoff[4];
#pragma unroll
  for (int ks = 0; ks < 4; ks++)
    rdoff[ks] = l31 * 128 + (((2 * ks + hi) ^ (l31 & 7)) << 4);

  bf16x8 qf[4];
  const int qbase = qt * 32;
#pragma unroll
  for (int st = 0; st < 4; st++)
    qf[st] = ldg8(&Qh[(size_t)(qbase + l31) * HD + st * 16 + hi * 8]);

  f32x16 o0, o1;
#pragma unroll
  for (int r = 0; r < 16; r++) { o0[r] = 0.f; o1[r] = 0.f; }
  float rl = 0.f;

#define CHUNKH(B, H, MASKED)                                                 \
  do {                                                                       \
    const char* kb = (const char*)&Kl[(B)][0] + (H) * 4096;                  \
    const char* vb = (const char*)&Vl[(B)][0] + (H) * 4096;                  \
    bf16x8 KF[4], VF[4];                                                     \
    _Pragma("unroll") for (int ks = 0; ks < 4; ks++) {                       \
      KF[ks] = __builtin_bit_cast(bf16x8, *(const u32x4*)(kb + rdoff[ks]));  \
      VF[ks] = __builtin_bit_cast(bf16x8, *(const u32x4*)(vb + rdoff[ks]));  \
    }                                                                        \
    f32x16 sa;                                                               \
    _Pragma("unroll") for (int r = 0; r < 16; r++) sa[r] = 0.f;              \
    __builtin_amdgcn_s_setprio(1);                                           \
    sa = mfma32(KF[0], qf[0], sa);                                           \
    sa = mfma32(KF[1], qf[1], sa);                                           \
    sa = mfma32(KF[2], qf[2], sa);                                           \
    sa = mfma32(KF[3], qf[3], sa);                                           \
    __builtin_amdgcn_s_setprio(0);                                           \
    float pv[16];                                                            \
    _Pragma("unroll") for (int r = 0; r < 16; r++) {                         \
      float arg = __builtin_fmaf(sa[r], SCL2, -FIXM);                        \
      if (MASKED) {                                                          \
        int key = (r & 3) + 8 * (r >> 2) + 4 * hi;                           \
        if (key > l31) arg = -1e30f;                                         \
      }                                                                      \
      pv[r] = exp2f(arg);                                                    \
      rl += pv[r];                                                           \
    }                                                                        \
    u32x4 pa0u, pa1u;                                                        \
    pa0u.x = pk2(pv[0], pv[1]);                                              \
    pa0u.y = pk2(pv[2], pv[3]);                                              \
    pa0u.z = pk2(pv[4], pv[5]);                                              \
    pa0u.w = pk2(pv[6], pv[7]);                                              \
    pa1u.x = pk2(pv[8], pv[9]);                                              \
    pa1u.y = pk2(pv[10], pv[11]);                                            \
    pa1u.z = pk2(pv[12], pv[13]);                                            \
    pa1u.w = pk2(pv[14], pv[15]);                                            \
    bf16x8 pa0 = __builtin_bit_cast(bf16x8, pa0u);                           \
    bf16x8 pa1 = __builtin_bit_cast(bf16x8, pa1u);                           \
    __builtin_amdgcn_s_setprio(1);                                           \
    o0 = mfma32(VF[0], pa0, o0);                                             \
    o0 = mfma32(VF[1], pa1, o0);                                             \
    o1 = mfma32(VF[2], pa0, o1);                                             \
    o1 = mfma32(VF[3], pa1, o1);                                             \
    __builtin_amdgcn_s_setprio(0);                                           \
  } while (0)

  STAGE(0, 0);
  __syncthreads();
  int cur = 0;
  const int halfq = qt >> 1, oddq = qt & 1;
  for (int kc2 = 0; kc2 <= kmax; kc2++) {
    if (kc2 < kmax) STAGE(cur ^ 1, kc2 + 1);
    if (kc2 < halfq) {
      CHUNKH(cur, 0, 0);
      CHUNKH(cur, 1, 0);
    } else if (kc2 == halfq) {
      if (oddq) {
        CHUNKH(cur, 0, 0);
        CHUNKH(cur, 1, 1);
      } else {
        CHUNKH(cur, 0, 1);
      }
    }
    __syncthreads();
    cur ^= 1;
  }

  float rlt = rl + __shfl_xor(rl, 32);
  float inv = 1.f / rlt;
  const size_t base =
      ((size_t)b_ * T_ + qbase + l31) * HIDDEN + h_ * HD + hi * 4;
#pragma unroll
  for (int gg = 0; gg < 4; gg++) {
    uint2 u;
    u.x = pk2(o0[4 * gg] * inv, o0[4 * gg + 1] * inv);
    u.y = pk2(o0[4 * gg + 2] * inv, o0[4 * gg + 3] * inv);
    *(uint2*)&Ao[base + gg * 8] = u;
  }
#pragma unroll
  for (int gg = 0; gg < 4; gg++) {
    uint2 u;
    u.x = pk2(o1[4 * gg] * inv, o1[4 * gg + 1] * inv);
    u.y = pk2(o1[4 * gg + 2] * inv, o1[4 * gg + 3] * inv);
    *(uint2*)&Ao[base + 32 + gg * 8] = u;
  }
#undef STAGE
#undef CHUNKH
}

extern "C" void kernel_launch(void* const* d_in, const int* in_sizes, int n_in,
                              void* d_out, int out_size, void* d_ws,
                              size_t ws_size, hipStream_t stream) {
  const float* data = (const float*)d_in[0];
  const float* qkvw = (const float*)d_in[1];
  const float* qkvb = (const float*)d_in[2];
  const float* outw = (const float*)d_in[3];
  const float* outb = (const float*)d_in[4];
  float* out = (float*)d_out;
  char* ws = (char*)d_ws;

  unsigned short* dataBf = (unsigned short*)(ws);             // 16 MiB, reused as attnO
  unsigned short* qkvwBf = (unsigned short*)(ws + 16777216);  // 6 MiB
  unsigned short* outwBf = (unsigned short*)(ws + 23068672);  // 2 MiB
  unsigned short* Qb = (unsigned short*)(ws + 25165824);      // 16 MiB
  unsigned short* Kb = (unsigned short*)(ws + 41943040);      // 16 MiB
  unsigned short* Vtb = (unsigned short*)(ws + 58720256);     // 16 MiB
  unsigned short* attnO = dataBf;  // safe: dataBf dead after QKV GEMM

  cvt3<<<2048, 256, 0, stream>>>(data, dataBf, (M_ROWS * HIDDEN) / 4, qkvw,
                                 qkvwBf, (3 * HIDDEN * HIDDEN) / 4, outw,
                                 outwBf, (HIDDEN * HIDDEN) / 4);

  gemmW<0, 12><<<768, 256, 0, stream>>>(dataBf, qkvwBf, qkvb, Qb, Kb, Vtb,
                                        nullptr);
  attn32<<<1024, 256, 0, stream>>>(Qb, Kb, Vtb, attnO);
  gemmW<1, 4><<<256, 256, 0, stream>>>(attnO, outwBf, outb, nullptr, nullptr,
                                       nullptr, out);
}